// Round 1
// baseline (6637.740 us; speedup 1.0000x reference)
//
#include <hip/hip_runtime.h>
#include <hip/hip_cooperative_groups.h>

#define B_   32
#define S_   512
#define V_   768
#define H_   512
#define M_   (B_*S_)      // 16384 rows
#define NALL 5120         // 2048 fwd gates | 2048 bwd gates | 1024 skip
#define KV   768
#define RWG  32           // recurrence workgroups (16 per direction)

typedef __bf16 bf16;
typedef __bf16 bf16x8 __attribute__((ext_vector_type(8)));
typedef __bf16 bf16x4v __attribute__((ext_vector_type(4)));
typedef float  f32x4  __attribute__((ext_vector_type(4)));

__device__ __forceinline__ float sigm(float x)  { return 1.0f / (1.0f + __expf(-x)); }
// stable: 2x->+inf => 1-2/inf = 1 ; 2x->-inf => 1-2/1 = -1  (no NaN)
__device__ __forceinline__ float tanh_(float x) { return 1.0f - 2.0f / (__expf(2.0f*x) + 1.0f); }

// ---------------- prep: fp32 -> bf16 cast of values ----------------
__global__ void k_cvt_values(const float* __restrict__ v, bf16* __restrict__ o, int n) {
    int i = (blockIdx.x * blockDim.x + threadIdx.x) * 4;
    if (i < n) {
        float4 f = *(const float4*)(v + i);
        bf16x4v t;
        t[0] = (bf16)f.x; t[1] = (bf16)f.y; t[2] = (bf16)f.z; t[3] = (bf16)f.w;
        *(bf16x4v*)(o + i) = t;
    }
}

// ---------------- prep: build transposed+interleaved weight cat ----------------
// wcat rows n (0..5119), k-contig (bf16):
//   n <  4096 : dir d=n>>11, nl=n&2047, unit=nl>>2, gate=nl&3 -> Wx_d[:, gate*512+unit]
//   n >= 4096 : Ws[:, n-4096]
__global__ void k_prep_wcat(const float* __restrict__ Wx_f, const float* __restrict__ Wx_b,
                            const float* __restrict__ Ws,
                            const float* __restrict__ b_f, const float* __restrict__ b_b,
                            const float* __restrict__ bs,
                            bf16* __restrict__ wcat, float* __restrict__ biascat) {
    int idx = blockIdx.x * blockDim.x + threadIdx.x;   // 5120*96 threads
    int n = idx / 96, kc = idx % 96;
    if (n >= NALL) return;
    const float* src; int col, ldn;
    if (n < 4096) {
        int d = n >> 11, nl = n & 2047, unit = nl >> 2, gate = nl & 3;
        col = gate * H_ + unit; src = d ? Wx_b : Wx_f; ldn = 2048;
        if (kc == 0) biascat[n] = (d ? b_b : b_f)[col];
    } else {
        col = n - 4096; src = Ws; ldn = 1024;
        if (kc == 0) biascat[n] = bs[col];
    }
    int k0 = kc * 8;
    bf16x8 t;
    #pragma unroll
    for (int j = 0; j < 8; j++) t[j] = (bf16)src[(size_t)(k0 + j) * ldn + col];
    *(bf16x8*)(wcat + (size_t)n * KV + k0) = t;
}

// ---------------- prep: WhT (2 dirs x 2048 rows x 512 k), same interleave ----------------
__global__ void k_prep_wh(const float* __restrict__ Wh_f, const float* __restrict__ Wh_b,
                          bf16* __restrict__ whT) {
    int idx = blockIdx.x * blockDim.x + threadIdx.x;   // 4096*64 threads
    int n = idx >> 6, kc = idx & 63;
    if (n >= 4096) return;
    int d = n >> 11, nl = n & 2047, unit = nl >> 2, gate = nl & 3;
    int col = gate * H_ + unit;
    const float* src = d ? Wh_b : Wh_f;
    int k0 = kc * 8;
    bf16x8 t;
    #pragma unroll
    for (int j = 0; j < 8; j++) t[j] = (bf16)src[(size_t)(k0 + j) * 2048 + col];
    *(bf16x8*)(whT + (size_t)n * H_ + k0) = t;
}

// ---------------- big GEMM: XG[16384 x 5120] = vals_bf16 @ wcat^T + bias ----------------
#define BM 64
#define BN 64
#define BK 32
#define LDT 40   // padded LDS row stride (bf16 elems); 80B keeps 16B alignment

__launch_bounds__(256)
__global__ void k_gemm(const bf16* __restrict__ A, const bf16* __restrict__ Bw,
                       const float* __restrict__ bias, bf16* __restrict__ C) {
    __shared__ bf16 As[BM * LDT];
    __shared__ bf16 Bs[BN * LDT];
    int m0 = blockIdx.x * BM, n0 = blockIdx.y * BN;
    int tid = threadIdx.x;
    int wv = tid >> 6, lane = tid & 63, lm = lane & 15, q = lane >> 4;
    int wm = (wv >> 1) * 32, wn = (wv & 1) * 32;
    f32x4 acc[2][2] = {};
    int lr = tid >> 2, lc = (tid & 3) * 8;
    const bf16* Ag = A  + (size_t)(m0 + lr) * KV + lc;
    const bf16* Bg = Bw + (size_t)(n0 + lr) * KV + lc;
    for (int kb = 0; kb < KV; kb += BK) {
        *(bf16x8*)&As[lr * LDT + lc] = *(const bf16x8*)(Ag + kb);
        *(bf16x8*)&Bs[lr * LDT + lc] = *(const bf16x8*)(Bg + kb);
        __syncthreads();
        bf16x8 af[2], bfr[2];
        af[0]  = *(bf16x8*)&As[(wm      + lm) * LDT + q * 8];
        af[1]  = *(bf16x8*)&As[(wm + 16 + lm) * LDT + q * 8];
        bfr[0] = *(bf16x8*)&Bs[(wn      + lm) * LDT + q * 8];
        bfr[1] = *(bf16x8*)&Bs[(wn + 16 + lm) * LDT + q * 8];
        #pragma unroll
        for (int mt = 0; mt < 2; mt++)
            #pragma unroll
            for (int nt = 0; nt < 2; nt++)
                acc[mt][nt] = __builtin_amdgcn_mfma_f32_16x16x32_bf16(af[mt], bfr[nt], acc[mt][nt], 0, 0, 0);
        __syncthreads();
    }
    #pragma unroll
    for (int mt = 0; mt < 2; mt++)
        #pragma unroll
        for (int nt = 0; nt < 2; nt++) {
            int col = n0 + wn + nt * 16 + lm;
            float bv = bias[col];
            #pragma unroll
            for (int r = 0; r < 4; r++) {
                int row = m0 + wm + mt * 16 + q * 4 + r;
                C[(size_t)row * NALL + col] = (bf16)(acc[mt][nt][r] + bv);
            }
        }
}

// ---------------- cooperative recurrence ----------------
// 32 WGs: d = wg>>4 (0 fwd, 1 bwd), slice sl = wg&15 owns units [sl*32, sl*32+32)
// per step: h(32x512, LDS) x WhT slice(128x512, from L2) -> 128 gate cols, M=32
__launch_bounds__(256)
__global__ void k_rnn(const bf16* __restrict__ XG, const bf16* __restrict__ WhT,
                      const float* __restrict__ alphas,
                      bf16* __restrict__ hex, bf16* __restrict__ outf, bf16* __restrict__ outb) {
    namespace cg = cooperative_groups;
    cg::grid_group grid = cg::this_grid();
    __shared__ bf16  hs[32 * 520];    // staged h, padded rows (2-way bank alias = free)
    __shared__ float gb[32 * 128];    // gate accumulators (batch-major, col_local = u*4+gate)
    __shared__ float cst[32 * 32];    // cell state (batch x unit_local)
    __shared__ float alf[32];

    int wg = blockIdx.x;
    int d = wg >> 4, sl = wg & 15;
    int tid = threadIdx.x;
    int wv = tid >> 6, lane = tid & 63, lm = lane & 15, q = lane >> 4;
    const bf16* whbase = WhT + (size_t)(d * 2048 + sl * 128) * H_;
    bf16* outp = d ? outb : outf;

    for (int i = tid; i < 32 * 32; i += 256) cst[i] = 0.f;

    for (int t = 0; t < S_; t++) {
        int s = d ? (S_ - 1 - t) : t;
        const bf16* hprev = hex + (size_t)(d * 2 + (t & 1)) * (32 * H_);
        bf16*       hnext = hex + (size_t)(d * 2 + ((t + 1) & 1)) * (32 * H_);
        // stage h (32x512 bf16) into LDS
        for (int c = tid; c < 2048; c += 256) {
            int row = c >> 6, kc = (c & 63) * 8;
            *(bf16x8*)&hs[row * 520 + kc] = *(const bf16x8*)(hprev + row * H_ + kc);
        }
        if (tid < 32) alf[tid] = alphas[tid * S_ + s];
        __syncthreads();

        f32x4 acc[2][2] = {};
        int wn = wv * 32;
        #pragma unroll 4
        for (int kt = 0; kt < 16; kt++) {
            int k0 = kt * 32;
            bf16x8 af[2], bfg[2];
            af[0]  = *(bf16x8*)&hs[lm * 520 + k0 + q * 8];
            af[1]  = *(bf16x8*)&hs[(16 + lm) * 520 + k0 + q * 8];
            bfg[0] = *(const bf16x8*)(whbase + (size_t)(wn      + lm) * H_ + k0 + q * 8);
            bfg[1] = *(const bf16x8*)(whbase + (size_t)(wn + 16 + lm) * H_ + k0 + q * 8);
            #pragma unroll
            for (int mt = 0; mt < 2; mt++)
                #pragma unroll
                for (int nt = 0; nt < 2; nt++)
                    acc[mt][nt] = __builtin_amdgcn_mfma_f32_16x16x32_bf16(af[mt], bfg[nt], acc[mt][nt], 0, 0, 0);
        }
        #pragma unroll
        for (int mt = 0; mt < 2; mt++)
            #pragma unroll
            for (int nt = 0; nt < 2; nt++)
                #pragma unroll
                for (int r = 0; r < 4; r++)
                    gb[(mt * 16 + q * 4 + r) * 128 + wn + nt * 16 + lm] = acc[mt][nt][r];
        __syncthreads();

        // elementwise gates for 1024 (batch, unit) pairs
        #pragma unroll
        for (int it = 0; it < 4; it++) {
            int idx = tid + it * 256;
            int b = idx >> 5, u = idx & 31;
            const bf16* xgp = XG + (size_t)(b * S_ + s) * NALL + d * 2048 + sl * 128 + u * 4;
            bf16x4v xv = *(const bf16x4v*)xgp;
            float gi = gb[b * 128 + u * 4 + 0] + (float)xv[0];
            float gf = gb[b * 128 + u * 4 + 1] + (float)xv[1];
            float gg = gb[b * 128 + u * 4 + 2] + (float)xv[2];
            float go = gb[b * 128 + u * 4 + 3] + (float)xv[3];
            float c  = cst[b * 32 + u];
            float cn = sigm(gf) * c + sigm(gi) * tanh_(gg);
            float hn = sigm(go) * tanh_(cn);
            float a  = alf[b];
            float hp = (float)hs[b * 520 + sl * 32 + u];   // previous h for own unit
            float c2 = (a > 0.f) ? cn : c;                 // alpha is exactly 0 or 1
            float h2 = (a > 0.f) ? hn : hp;
            cst[b * 32 + u] = c2;
            bf16 h2b = (bf16)h2;
            hnext[b * H_ + sl * 32 + u] = h2b;
            outp[(size_t)(b * S_ + s) * H_ + sl * 32 + u] = h2b;
        }
        grid.sync();
    }
}

// ---------------- pooling ----------------
__launch_bounds__(256)
__global__ void k_pool(const bf16* __restrict__ outf, const bf16* __restrict__ outb,
                       const bf16* __restrict__ XG, const float* __restrict__ alphas,
                       float* __restrict__ out) {
    __shared__ float al[S_];
    int b = blockIdx.x;
    int j = blockIdx.y * 256 + threadIdx.x;     // 0..1023
    for (int i = threadIdx.x; i < S_; i += 256) al[i] = alphas[b * S_ + i];
    __syncthreads();
    int jj = (j < H_) ? j : j - H_;
    const bf16* tp = (j < H_) ? outf : outb;
    size_t base = (size_t)b * S_;
    float sum = 0.f, mx = -INFINITY, asum = 0.f;
    for (int s = 0; s < S_; s++) {
        float a = al[s]; asum += a;
        float r = (float)tp[(base + s) * H_ + jj] + (float)XG[(base + s) * NALL + 4096 + j];
        if (a > 0.f) { sum += r; mx = fmaxf(mx, r); }
    }
    float mean = sum / (asum + 1e-6f);
    if (mx == -INFINITY) mx = 0.f;
    out[b * 2048 + j] = mean;
    out[b * 2048 + 1024 + j] = mx;
}

extern "C" void kernel_launch(void* const* d_in, const int* in_sizes, int n_in,
                              void* d_out, int out_size, void* d_ws, size_t ws_size,
                              hipStream_t stream) {
    const float* values = (const float*)d_in[0];
    const float* alphas = (const float*)d_in[1];
    const float* Wx_f   = (const float*)d_in[2];
    const float* Wh_f   = (const float*)d_in[3];
    const float* b_f    = (const float*)d_in[4];
    const float* Wx_b   = (const float*)d_in[5];
    const float* Wh_b   = (const float*)d_in[6];
    const float* b_b    = (const float*)d_in[7];
    const float* Ws     = (const float*)d_in[8];
    const float* bs     = (const float*)d_in[9];
    float* out = (float*)d_out;

    char* ws = (char*)d_ws;
    size_t off = 0;
    auto alloc = [&](size_t bytes) { size_t p = off; off += (bytes + 255) & ~(size_t)255; return p; };
    bf16*  valsbf  = (bf16*)(ws + alloc((size_t)M_ * KV * 2));        // 25.2 MB
    bf16*  wcat    = (bf16*)(ws + alloc((size_t)NALL * KV * 2));      // 7.9 MB
    bf16*  whT     = (bf16*)(ws + alloc((size_t)4096 * H_ * 2));      // 4.2 MB
    float* biascat = (float*)(ws + alloc((size_t)NALL * 4));
    bf16*  xg      = (bf16*)(ws + alloc((size_t)M_ * NALL * 2));      // 167.8 MB
    bf16*  outfp   = (bf16*)(ws + alloc((size_t)M_ * H_ * 2));        // 16.8 MB
    bf16*  outbp   = (bf16*)(ws + alloc((size_t)M_ * H_ * 2));        // 16.8 MB
    bf16*  hex     = (bf16*)(ws + alloc((size_t)4 * 32 * H_ * 2));    // 128 KB

    hipMemsetAsync(hex, 0, (size_t)4 * 32 * H_ * 2, stream);
    k_cvt_values<<<(M_ * KV) / (256 * 4), 256, 0, stream>>>(values, valsbf, M_ * KV);
    k_prep_wcat<<<(NALL * 96) / 256, 256, 0, stream>>>(Wx_f, Wx_b, Ws, b_f, b_b, bs, wcat, biascat);
    k_prep_wh<<<(4096 * 64) / 256, 256, 0, stream>>>(Wh_f, Wh_b, whT);
    dim3 gg(M_ / BM, NALL / BN);
    k_gemm<<<gg, 256, 0, stream>>>(valsbf, wcat, biascat, xg);
    void* args[] = { (void*)&xg, (void*)&whT, (void*)&alphas, (void*)&hex, (void*)&outfp, (void*)&outbp };
    hipLaunchCooperativeKernel((void*)k_rnn, dim3(RWG), dim3(256), args, 0, stream);
    dim3 gp(B_, 1024 / 256);
    k_pool<<<gp, 256, 0, stream>>>(outfp, outbp, xg, alphas, out);
}

// Round 2
// 4971.899 us; speedup vs baseline: 1.3351x; 1.3351x over previous
//
#include <hip/hip_runtime.h>

#define B_   32
#define S_   512
#define V_   768
#define H_   512
#define M_   (B_*S_)      // 16384 rows
#define NALL 5120         // 2048 fwd gates | 2048 bwd gates | 1024 skip
#define KV   768
#define RWG  32           // recurrence workgroups (16 per direction)

typedef __bf16 bf16;
typedef __bf16 bf16x8 __attribute__((ext_vector_type(8)));
typedef __bf16 bf16x4v __attribute__((ext_vector_type(4)));
typedef float  f32x4  __attribute__((ext_vector_type(4)));

__device__ __forceinline__ float sigm(float x)  { return 1.0f / (1.0f + __expf(-x)); }
// stable: 2x->+inf => 1-2/inf = 1 ; 2x->-inf => 1-2/1 = -1  (no NaN)
__device__ __forceinline__ float tanh_(float x) { return 1.0f - 2.0f / (__expf(2.0f*x) + 1.0f); }

// ---------------- prep: fp32 -> bf16 cast of values ----------------
__global__ void k_cvt_values(const float* __restrict__ v, bf16* __restrict__ o, int n) {
    int i = (blockIdx.x * blockDim.x + threadIdx.x) * 4;
    if (i < n) {
        float4 f = *(const float4*)(v + i);
        bf16x4v t;
        t[0] = (bf16)f.x; t[1] = (bf16)f.y; t[2] = (bf16)f.z; t[3] = (bf16)f.w;
        *(bf16x4v*)(o + i) = t;
    }
}

// ---------------- prep: build transposed+interleaved weight cat ----------------
__global__ void k_prep_wcat(const float* __restrict__ Wx_f, const float* __restrict__ Wx_b,
                            const float* __restrict__ Ws,
                            const float* __restrict__ b_f, const float* __restrict__ b_b,
                            const float* __restrict__ bs,
                            bf16* __restrict__ wcat, float* __restrict__ biascat) {
    int idx = blockIdx.x * blockDim.x + threadIdx.x;   // 5120*96 threads
    int n = idx / 96, kc = idx % 96;
    if (n >= NALL) return;
    const float* src; int col, ldn;
    if (n < 4096) {
        int d = n >> 11, nl = n & 2047, unit = nl >> 2, gate = nl & 3;
        col = gate * H_ + unit; src = d ? Wx_b : Wx_f; ldn = 2048;
        if (kc == 0) biascat[n] = (d ? b_b : b_f)[col];
    } else {
        col = n - 4096; src = Ws; ldn = 1024;
        if (kc == 0) biascat[n] = bs[col];
    }
    int k0 = kc * 8;
    bf16x8 t;
    #pragma unroll
    for (int j = 0; j < 8; j++) t[j] = (bf16)src[(size_t)(k0 + j) * ldn + col];
    *(bf16x8*)(wcat + (size_t)n * KV + k0) = t;
}

// ---------------- prep: WhT (2 dirs x 2048 rows x 512 k), same interleave ----------------
__global__ void k_prep_wh(const float* __restrict__ Wh_f, const float* __restrict__ Wh_b,
                          bf16* __restrict__ whT) {
    int idx = blockIdx.x * blockDim.x + threadIdx.x;   // 4096*64 threads
    int n = idx >> 6, kc = idx & 63;
    if (n >= 4096) return;
    int d = n >> 11, nl = n & 2047, unit = nl >> 2, gate = nl & 3;
    int col = gate * H_ + unit;
    const float* src = d ? Wh_b : Wh_f;
    int k0 = kc * 8;
    bf16x8 t;
    #pragma unroll
    for (int j = 0; j < 8; j++) t[j] = (bf16)src[(size_t)(k0 + j) * 2048 + col];
    *(bf16x8*)(whT + (size_t)n * H_ + k0) = t;
}

// ---------------- big GEMM: XG[16384 x 5120] = vals_bf16 @ wcat^T + bias ----------------
#define BM 64
#define BN 64
#define BK 32
#define LDT 40

__launch_bounds__(256)
__global__ void k_gemm(const bf16* __restrict__ A, const bf16* __restrict__ Bw,
                       const float* __restrict__ bias, bf16* __restrict__ C) {
    __shared__ bf16 As[BM * LDT];
    __shared__ bf16 Bs[BN * LDT];
    int m0 = blockIdx.x * BM, n0 = blockIdx.y * BN;
    int tid = threadIdx.x;
    int wv = tid >> 6, lane = tid & 63, lm = lane & 15, q = lane >> 4;
    int wm = (wv >> 1) * 32, wn = (wv & 1) * 32;
    f32x4 acc[2][2] = {};
    int lr = tid >> 2, lc = (tid & 3) * 8;
    const bf16* Ag = A  + (size_t)(m0 + lr) * KV + lc;
    const bf16* Bg = Bw + (size_t)(n0 + lr) * KV + lc;
    for (int kb = 0; kb < KV; kb += BK) {
        *(bf16x8*)&As[lr * LDT + lc] = *(const bf16x8*)(Ag + kb);
        *(bf16x8*)&Bs[lr * LDT + lc] = *(const bf16x8*)(Bg + kb);
        __syncthreads();
        bf16x8 af[2], bfr[2];
        af[0]  = *(bf16x8*)&As[(wm      + lm) * LDT + q * 8];
        af[1]  = *(bf16x8*)&As[(wm + 16 + lm) * LDT + q * 8];
        bfr[0] = *(bf16x8*)&Bs[(wn      + lm) * LDT + q * 8];
        bfr[1] = *(bf16x8*)&Bs[(wn + 16 + lm) * LDT + q * 8];
        #pragma unroll
        for (int mt = 0; mt < 2; mt++)
            #pragma unroll
            for (int nt = 0; nt < 2; nt++)
                acc[mt][nt] = __builtin_amdgcn_mfma_f32_16x16x32_bf16(af[mt], bfr[nt], acc[mt][nt], 0, 0, 0);
        __syncthreads();
    }
    #pragma unroll
    for (int mt = 0; mt < 2; mt++)
        #pragma unroll
        for (int nt = 0; nt < 2; nt++) {
            int col = n0 + wn + nt * 16 + lm;
            float bv = bias[col];
            #pragma unroll
            for (int r = 0; r < 4; r++) {
                int row = m0 + wm + mt * 16 + q * 4 + r;
                C[(size_t)row * NALL + col] = (bf16)(acc[mt][nt][r] + bv);
            }
        }
}

// ---------------- cooperative recurrence, flag-sync version ----------------
// 32 WGs: d = wg>>4 (0 fwd, 1 bwd), slice sl = wg&15 owns units [sl*32, sl*32+32)
// No grid.sync: per-slice monotonic flags. Producer: write h slice -> threadfence
// -> syncthreads -> flag=t+1. Consumer: poll 16 flags >= t -> syncthreads ->
// acquire threadfence -> read h. fwd/bwd pipelines fully independent.
// Wh slice (32KB/wave) lives in 128 persistent VGPRs: zero weight traffic in loop.
__launch_bounds__(256, 1)
__global__ void k_rnn(const bf16* __restrict__ XG, const bf16* __restrict__ WhT,
                      const float* __restrict__ alphas,
                      bf16* __restrict__ hex, int* __restrict__ flags,
                      bf16* __restrict__ outf, bf16* __restrict__ outb) {
    __shared__ bf16  hs[32 * 520];    // staged h
    __shared__ float gb[32 * 132];    // gate accumulators (pad 132 kills 4-way conflict)
    __shared__ float cst[32 * 32];    // cell state (batch x unit_local)
    __shared__ float alf[32];

    int wg = blockIdx.x;
    int d = wg >> 4, sl = wg & 15;
    int tid = threadIdx.x;
    int wv = tid >> 6, lane = tid & 63, lm = lane & 15, q = lane >> 4;
    int wn = wv * 32;
    const bf16* whbase = WhT + (size_t)(d * 2048 + sl * 128) * H_;
    bf16* outp = d ? outb : outf;
    int* myflags = flags + d * 64;    // 256B apart: no false sharing between dirs

    // persistent Wh fragments: 2 x 16 x bf16x8 = 128 VGPRs/lane
    bf16x8 wr0[16], wr1[16];
    #pragma unroll
    for (int kt = 0; kt < 16; kt++) {
        wr0[kt] = *(const bf16x8*)(whbase + (size_t)(wn      + lm) * H_ + kt * 32 + q * 8);
        wr1[kt] = *(const bf16x8*)(whbase + (size_t)(wn + 16 + lm) * H_ + kt * 32 + q * 8);
    }

    for (int i = tid; i < 32 * 32; i += 256) cst[i] = 0.f;   // same-thread reuse mapping

    for (int t = 0; t < S_; t++) {
        int s = d ? (S_ - 1 - t) : t;
        const bf16* hprev = hex + (size_t)(d * 2 + (t & 1)) * (32 * H_);
        bf16*       hnext = hex + (size_t)(d * 2 + ((t + 1) & 1)) * (32 * H_);

        // prefetch XG gate inputs + alphas (independent of h) to hide under poll
        bf16x4v xv[4];
        #pragma unroll
        for (int it = 0; it < 4; it++) {
            int idx = tid + it * 256;
            int b = idx >> 5, u = idx & 31;
            xv[it] = *(const bf16x4v*)(XG + (size_t)(b * S_ + s) * NALL + d * 2048 + sl * 128 + u * 4);
        }
        if (tid < 32) alf[tid] = alphas[tid * S_ + s];

        if (t > 0) {
            if (tid < 16)
                while (__hip_atomic_load(&myflags[tid], __ATOMIC_RELAXED, __HIP_MEMORY_SCOPE_AGENT) < t)
                    __builtin_amdgcn_s_sleep(1);
            __syncthreads();
            __threadfence();   // acquire side: invalidate so h reads see L3-fresh data
        }

        // stage h_t (32x512 bf16 = 32KB) into LDS
        for (int c = tid; c < 2048; c += 256) {
            int row = c >> 6, kc = (c & 63) * 8;
            *(bf16x8*)&hs[row * 520 + kc] = *(const bf16x8*)(hprev + row * H_ + kc);
        }
        __syncthreads();

        f32x4 acc[2][2] = {};
        #pragma unroll
        for (int kt = 0; kt < 16; kt++) {
            bf16x8 a0 = *(bf16x8*)&hs[(     lm) * 520 + kt * 32 + q * 8];
            bf16x8 a1 = *(bf16x8*)&hs[(16 + lm) * 520 + kt * 32 + q * 8];
            acc[0][0] = __builtin_amdgcn_mfma_f32_16x16x32_bf16(a0, wr0[kt], acc[0][0], 0, 0, 0);
            acc[0][1] = __builtin_amdgcn_mfma_f32_16x16x32_bf16(a0, wr1[kt], acc[0][1], 0, 0, 0);
            acc[1][0] = __builtin_amdgcn_mfma_f32_16x16x32_bf16(a1, wr0[kt], acc[1][0], 0, 0, 0);
            acc[1][1] = __builtin_amdgcn_mfma_f32_16x16x32_bf16(a1, wr1[kt], acc[1][1], 0, 0, 0);
        }
        #pragma unroll
        for (int mt = 0; mt < 2; mt++)
            #pragma unroll
            for (int nt = 0; nt < 2; nt++)
                #pragma unroll
                for (int r = 0; r < 4; r++)
                    gb[(mt * 16 + q * 4 + r) * 132 + wn + nt * 16 + lm] = acc[mt][nt][r];
        __syncthreads();

        // elementwise gates for 1024 (batch, unit) pairs
        #pragma unroll
        for (int it = 0; it < 4; it++) {
            int idx = tid + it * 256;
            int b = idx >> 5, u = idx & 31;
            float gi = gb[b * 132 + u * 4 + 0] + (float)xv[it][0];
            float gf = gb[b * 132 + u * 4 + 1] + (float)xv[it][1];
            float gg = gb[b * 132 + u * 4 + 2] + (float)xv[it][2];
            float go = gb[b * 132 + u * 4 + 3] + (float)xv[it][3];
            float c  = cst[b * 32 + u];
            float cn = sigm(gf) * c + sigm(gi) * tanh_(gg);
            float hn = sigm(go) * tanh_(cn);
            float a  = alf[b];
            float hp = (float)hs[b * 520 + sl * 32 + u];   // previous h for own unit
            float c2 = (a > 0.f) ? cn : c;                 // alpha is exactly 0 or 1
            float h2 = (a > 0.f) ? hn : hp;
            cst[b * 32 + u] = c2;
            bf16 h2b = (bf16)h2;
            hnext[b * H_ + sl * 32 + u] = h2b;
            outp[(size_t)(b * S_ + s) * H_ + sl * 32 + u] = h2b;
        }
        __threadfence();   // release side: h slice visible at agent scope
        __syncthreads();
        if (tid == 0)
            __hip_atomic_store(&flags[d * 64 + sl], t + 1, __ATOMIC_RELAXED, __HIP_MEMORY_SCOPE_AGENT);
    }
}

// ---------------- pooling ----------------
__launch_bounds__(256)
__global__ void k_pool(const bf16* __restrict__ outf, const bf16* __restrict__ outb,
                       const bf16* __restrict__ XG, const float* __restrict__ alphas,
                       float* __restrict__ out) {
    __shared__ float al[S_];
    int b = blockIdx.x;
    int j = blockIdx.y * 256 + threadIdx.x;     // 0..1023
    for (int i = threadIdx.x; i < S_; i += 256) al[i] = alphas[b * S_ + i];
    __syncthreads();
    int jj = (j < H_) ? j : j - H_;
    const bf16* tp = (j < H_) ? outf : outb;
    size_t base = (size_t)b * S_;
    float sum = 0.f, mx = -INFINITY, asum = 0.f;
    for (int s = 0; s < S_; s++) {
        float a = al[s]; asum += a;
        float r = (float)tp[(base + s) * H_ + jj] + (float)XG[(base + s) * NALL + 4096 + j];
        if (a > 0.f) { sum += r; mx = fmaxf(mx, r); }
    }
    float mean = sum / (asum + 1e-6f);
    if (mx == -INFINITY) mx = 0.f;
    out[b * 2048 + j] = mean;
    out[b * 2048 + 1024 + j] = mx;
}

extern "C" void kernel_launch(void* const* d_in, const int* in_sizes, int n_in,
                              void* d_out, int out_size, void* d_ws, size_t ws_size,
                              hipStream_t stream) {
    const float* values = (const float*)d_in[0];
    const float* alphas = (const float*)d_in[1];
    const float* Wx_f   = (const float*)d_in[2];
    const float* Wh_f   = (const float*)d_in[3];
    const float* b_f    = (const float*)d_in[4];
    const float* Wx_b   = (const float*)d_in[5];
    const float* Wh_b   = (const float*)d_in[6];
    const float* b_b    = (const float*)d_in[7];
    const float* Ws     = (const float*)d_in[8];
    const float* bs     = (const float*)d_in[9];
    float* out = (float*)d_out;

    char* ws = (char*)d_ws;
    size_t off = 0;
    auto alloc = [&](size_t bytes) { size_t p = off; off += (bytes + 255) & ~(size_t)255; return p; };
    bf16*  valsbf  = (bf16*)(ws + alloc((size_t)M_ * KV * 2));
    bf16*  wcat    = (bf16*)(ws + alloc((size_t)NALL * KV * 2));
    bf16*  whT     = (bf16*)(ws + alloc((size_t)4096 * H_ * 2));
    float* biascat = (float*)(ws + alloc((size_t)NALL * 4));
    bf16*  xg      = (bf16*)(ws + alloc((size_t)M_ * NALL * 2));
    bf16*  outfp   = (bf16*)(ws + alloc((size_t)M_ * H_ * 2));
    bf16*  outbp   = (bf16*)(ws + alloc((size_t)M_ * H_ * 2));
    bf16*  hex     = (bf16*)(ws + alloc((size_t)4 * 32 * H_ * 2));
    int*   flags   = (int*)(ws + alloc(128 * 4));

    hipMemsetAsync(hex, 0, (size_t)4 * 32 * H_ * 2, stream);
    hipMemsetAsync(flags, 0, 128 * 4, stream);
    k_cvt_values<<<(M_ * KV) / (256 * 4), 256, 0, stream>>>(values, valsbf, M_ * KV);
    k_prep_wcat<<<(NALL * 96) / 256, 256, 0, stream>>>(Wx_f, Wx_b, Ws, b_f, b_b, bs, wcat, biascat);
    k_prep_wh<<<(4096 * 64) / 256, 256, 0, stream>>>(Wh_f, Wh_b, whT);
    dim3 gg(M_ / BM, NALL / BN);
    k_gemm<<<gg, 256, 0, stream>>>(valsbf, wcat, biascat, xg);
    void* args[] = { (void*)&xg, (void*)&whT, (void*)&alphas, (void*)&hex, (void*)&flags,
                     (void*)&outfp, (void*)&outbp };
    hipLaunchCooperativeKernel((void*)k_rnn, dim3(RWG), dim3(256), args, 0, stream);
    dim3 gp(B_, 1024 / 256);
    k_pool<<<gp, 256, 0, stream>>>(outfp, outbp, xg, alphas, out);
}